// Round 15
// baseline (180.496 us; speedup 1.0000x reference)
//
#include <hip/hip_runtime.h>

#define T_LEN 2048
#define B_SZ  2048
#define H_SZ  8
#define WARM  12      // layer l live from tick 3l; outputs from tick 12
#define XS_N  2080    // xs zero-padded; reads up to xs[2067]

// row_ror:(CTRL-0x120) within 16-lane rows; 8-periodic data -> rotate mod 8
template<int CTRL>
__device__ __forceinline__ float rot_dpp(float v) {
    return __int_as_float(
        __builtin_amdgcn_update_dpp(0, __float_as_int(v), CTRL, 0xF, 0xF, false));
}

__global__ __launch_bounds__(64, 1)
void rnn_fasm2(const float* __restrict__ x,
               const float* __restrict__ h0_in,
               const float* __restrict__ w_ih0,
               const float* __restrict__ w_ih,
               const float* __restrict__ w_hh,
               const float* __restrict__ b_ih,
               const float* __restrict__ b_hh,
               const float* __restrict__ w_lin,
               const float* __restrict__ b_lin,
               float* __restrict__ out)
{
    __shared__ __align__(16) float xs[XS_N];

    const int lane = threadIdx.x;
    const int u    = lane & 7;            // hidden unit
    const int l    = lane >> 4;           // row = layer
    const bool grB = ((lane >> 3) & 1);   // A-half: own dot (+base), B-half: export dot
    const int lp   = (l + 3) & 3;         // import source row (row0 <- row3 = output)
    const int bidx = (((lp << 4) | 8 | u)) << 2;   // pull from source row's B-half

    for (int i = lane; i < XS_N; i += 64) xs[i] = 0.0f;
    __syncthreads();
    for (int i = lane; i < T_LEN; i += 64) xs[i] = x[(size_t)i * B_SZ + (B_SZ - 1)];
    __syncthreads();

    // DPP direction probe (HW-verified round 3); asm row_ror:s == ctrl 0x120+s
    int rot1 = __builtin_amdgcn_update_dpp(0, lane, 0x121, 0xF, 0xF, false);
    const bool plus = ((rot1 & 15) == ((lane + 1) & 15));

    const float C   = 2.0f * 1.4426950408889634f;  // h=tanh(a) -> r=rcp(exp2(C*a)+1)
    const float m2C = -2.0f * C;

    float whh_rs = 0.0f, wih_rs = 0.0f, wlin_rs = 0.0f;
    #pragma unroll
    for (int j = 0; j < 8; ++j) {
        whh_rs += w_hh[(l * H_SZ + u) * H_SZ + j];
        if (l > 0) wih_rs += w_ih[((l - 1) * H_SZ + u) * H_SZ + j];
        wlin_rs += w_lin[j];
    }
    const float bl_tot = wlin_rs + b_lin[0];

    // per-lane dot weights: A-half = own recurrence (-2C*whh), B-half = export
    float wsel[8];
    #pragma unroll
    for (int s = 0; s < 8; ++s) {
        int j = plus ? ((u + s) & 7) : ((u - s) & 7);
        float whh2  = m2C * w_hh[(l * H_SZ + u) * H_SZ + j];
        float wexp2 = (l < 3) ? m2C * w_ih[(l * H_SZ + u) * H_SZ + j]
                              : -2.0f * w_lin[j];
        wsel[s] = grB ? wexp2 : whh2;
    }
    const float tbase = (grB && l == 3) ? bl_tot : 0.0f;   // output bias on row-3 export
    const float xconst_a = C * (b_ih[l * H_SZ + u] + b_hh[l * H_SZ + u]
                                + whh_rs + ((l > 0) ? wih_rs : 0.0f));
    // dual-duty constants: A-half -> base terms, B-half -> tbase (no cndmask in loop)
    const float wx2p    = (!grB && l == 0) ? C * w_ih0[u] : 0.0f;
    const float xconstp = grB ? tbase : xconst_a;
    const float selp    = (grB || l == 0) ? 0.0f : 1.0f;   // row0 import = OUTPUT, not y-term

    // state r = (1 - h)/2
    float r = __builtin_fmaf(-0.5f, h0_in[((size_t)l * B_SZ + (B_SZ - 1)) * H_SZ + u], 0.5f);

    // tick asm (15 ops): no top s_nop — rcp(r)->DPP(r) spacing is guaranteed by the
    // >=2 instructions that must sit between consecutive asms (bpermute on S, base-fma
    // on t) plus the leading non-DPP fma. exp2->DPP(e) hazard: t-fma + s_nop 0 = exactly
    // 2 wait states (R14-proven). Bank-masked ror8 gives B-half exp2(S_A).
    auto tick = [&](float& ip_slot, float base, float xv_next, float& t_out) -> float {
        float c0 = base, c1, S, e, t, rn;
        asm("v_fma_f32      %[c0], %[w0], %[r], %[c0]\n\t"
            "v_mul_f32_dpp  %[c1], %[r], %[w4] row_ror:4 row_mask:0xf bank_mask:0xf\n\t"
            "v_fmac_f32_dpp %[c0], %[r], %[w1] row_ror:1 row_mask:0xf bank_mask:0xf\n\t"
            "v_fmac_f32_dpp %[c1], %[r], %[w5] row_ror:5 row_mask:0xf bank_mask:0xf\n\t"
            "v_fmac_f32_dpp %[c0], %[r], %[w2] row_ror:2 row_mask:0xf bank_mask:0xf\n\t"
            "v_fmac_f32_dpp %[c1], %[r], %[w6] row_ror:6 row_mask:0xf bank_mask:0xf\n\t"
            "v_fmac_f32_dpp %[c0], %[r], %[w3] row_ror:3 row_mask:0xf bank_mask:0xf\n\t"
            "v_fmac_f32_dpp %[c1], %[r], %[w7] row_ror:7 row_mask:0xf bank_mask:0xf\n\t"
            "v_add_f32      %[S], %[c0], %[c1]\n\t"
            "v_exp_f32      %[e], %[S]\n\t"
            "v_fma_f32      %[t], %[wx], %[xv], %[xc]\n\t"
            "s_nop 0\n\t"
            "v_mov_b32_dpp  %[e], %[e] row_ror:8 row_mask:0xf bank_mask:0xc\n\t"
            "v_add_f32      %[e], 1.0, %[e]\n\t"
            "v_rcp_f32      %[rn], %[e]"
            : [c0]"+v"(c0), [c1]"=&v"(c1), [S]"=&v"(S), [e]"=&v"(e),
              [t]"=&v"(t), [rn]"=&v"(rn)
            : [r]"v"(r), [w0]"v"(wsel[0]), [w1]"v"(wsel[1]), [w2]"v"(wsel[2]),
              [w3]"v"(wsel[3]), [w4]"v"(wsel[4]), [w5]"v"(wsel[5]),
              [w6]"v"(wsel[6]), [w7]"v"(wsel[7]),
              [wx]"v"(wx2p), [xv]"v"(xv_next), [xc]"v"(xconstp));
        ip_slot = __int_as_float(__builtin_amdgcn_ds_bpermute(bidx, __float_as_int(S)));
        t_out = t;
        return rn;
    };

    // ---- warm-up ticks 0..11 (2-slot scheme): layer l live from tick 3l ----
    float ipA = 0.0f, ipB = 0.0f;
    float baseA = __builtin_fmaf(wx2p, xs[0], xconstp);  // tick 0 base (ip=0)
    float baseB = 0.0f;                                  // set before first use
    #pragma unroll
    for (int k = 0; k < WARM; ++k) {
        float rn, t;
        if (k & 1) { rn = tick(ipB, baseB, xs[k + 1], t); baseA = __builtin_fmaf(selp, ipA, t); }
        else       { rn = tick(ipA, baseA, xs[k + 1], t); baseB = __builtin_fmaf(selp, ipB, t); }
        r = (k >= 3 * l) ? rn : r;
    }
    // handover to 8-slot renaming: bp@10, bp@11, base for tick 12
    float bpm2 = ipA;     // bp issued @ tick 10 -> out[0]
    float bpm1 = ipB;     // bp issued @ tick 11 -> out[1]
    float base0 = baseA;  // consumed at tick 12

    // ---- main: ticks 12..2059, 8/iter, 8-slot ip rotation (no capture movs).
    //      out[kb-12+j] = bp issued @ tick kb+j-2; base_{j+1} = fma(selp, bp@(j-1), t_j)
    const float4* xsv = (const float4*)xs;
    float4 xq  = xsv[3];   // xs[12..15]
    float4 xq2 = xsv[4];   // xs[16..19]
    for (int kb = WARM; kb <= 2052; kb += 8) {
        float4 xn1 = xsv[(kb >> 2) + 2];   // xs[kb+8 .. kb+11]
        float4 xn2 = xsv[(kb >> 2) + 3];   // xs[kb+12 .. kb+15]
        float ip0, ip1, ip2, ip3, ip4, ip5, ip6, ip7, t;
        float base1, base2, base3, base4, base5, base6, base7;
        r = tick(ip0, base0, xq.y,  t); base1 = __builtin_fmaf(selp, bpm1, t);
        r = tick(ip1, base1, xq.z,  t); base2 = __builtin_fmaf(selp, ip0, t);
        r = tick(ip2, base2, xq.w,  t); base3 = __builtin_fmaf(selp, ip1, t);
        r = tick(ip3, base3, xq2.x, t); base4 = __builtin_fmaf(selp, ip2, t);
        r = tick(ip4, base4, xq2.y, t); base5 = __builtin_fmaf(selp, ip3, t);
        r = tick(ip5, base5, xq2.z, t); base6 = __builtin_fmaf(selp, ip4, t);
        r = tick(ip6, base6, xq2.w, t); base7 = __builtin_fmaf(selp, ip5, t);
        r = tick(ip7, base7, xn1.x, t); base0 = __builtin_fmaf(selp, ip6, t);
        if (lane == 0) {
            *(float4*)(out + (kb - WARM))     = make_float4(bpm2, bpm1, ip0, ip1);
            *(float4*)(out + (kb - WARM) + 4) = make_float4(ip2, ip3, ip4, ip5);
        }
        bpm2 = ip6; bpm1 = ip7;
        xq = xn1; xq2 = xn2;
    }
}

extern "C" void kernel_launch(void* const* d_in, const int* in_sizes, int n_in,
                              void* d_out, int out_size, void* d_ws, size_t ws_size,
                              hipStream_t stream) {
    const float* x     = (const float*)d_in[0];
    const float* h0    = (const float*)d_in[1];
    const float* w_ih0 = (const float*)d_in[2];
    const float* w_ih  = (const float*)d_in[3];
    const float* w_hh  = (const float*)d_in[4];
    const float* b_ih  = (const float*)d_in[5];
    const float* b_hh  = (const float*)d_in[6];
    const float* w_lin = (const float*)d_in[7];
    const float* b_lin = (const float*)d_in[8];
    float* out = (float*)d_out;

    rnn_fasm2<<<dim3(1), dim3(64), 0, stream>>>(
        x, h0, w_ih0, w_ih, w_hh, b_ih, b_hh, w_lin, b_lin, out);
}